// Round 1
// baseline (2831.437 us; speedup 1.0000x reference)
//
#include <hip/hip_runtime.h>
#include <cstdint>
#include <cstddef>

typedef unsigned short u16;
typedef unsigned int u32;
typedef float f32x4 __attribute__((ext_vector_type(4)));
typedef __bf16 bf16x8 __attribute__((ext_vector_type(8)));

// ---------- helpers ----------
__device__ inline u16 f32_to_bf16(float f) {
  u32 u = __float_as_uint(f);
  u = (u + 0x7FFFu + ((u >> 16) & 1u)) >> 16;
  return (u16)u;
}

#define GLD16(src, dst)                                                        \
  __builtin_amdgcn_global_load_lds(                                            \
      (const __attribute__((address_space(1))) u32*)(src),                     \
      (__attribute__((address_space(3))) u32*)(dst), 16, 0, 0)

// Stage a 128(row) x 64(k) bf16 tile (16 KiB) into LDS with XOR swizzle:
// LDS linear byte d holds global k-byte (d&127) ^ ((row&7)<<4) of row d>>7.
// global_load_lds dest = wave-uniform base + lane*16; source is per-lane.
__device__ inline void stage_tile(const char* gbase, long stride_b, u16* tile,
                                  int tid) {
  const int wave = tid >> 6, lane = tid & 63;
  const int wbase = wave * 4096;
#pragma unroll
  for (int c = 0; c < 4; ++c) {
    const int d = wbase + c * 1024 + lane * 16;
    const int row = d >> 7;
    const int off = d & 127;
    const int kb = off ^ ((row & 7) << 4);
    const char* src = gbase + (long)row * stride_b + kb;
    char* dst = (char*)tile + wbase + c * 1024;  // wave-uniform
    GLD16(src, dst);
  }
}

// Fragment read: row = tile-local row (16-lane varies), 8 contiguous k per lane
// group p=lane>>4 at k = ks*32 + p*8 (+j). Same assumed k-map for A and B.
__device__ inline bf16x8 frag_ld(const u16* tile, int row, int ks, int p) {
  const int byte = row * 128 + (((ks << 6) + (p << 4)) ^ ((row & 7) << 4));
  return *(const bf16x8*)((const char*)tile + byte);
}

// ---------- x fp32 -> bf16 ----------
__global__ void k_convert_x(const float* __restrict__ x, u16* __restrict__ o) {
  const long i = (long)blockIdx.x * 256 + threadIdx.x;  // 8 elems per thread
  const float4 a = ((const float4*)x)[i * 2];
  const float4 b = ((const float4*)x)[i * 2 + 1];
  uint4 r;
  r.x = (u32)f32_to_bf16(a.x) | ((u32)f32_to_bf16(a.y) << 16);
  r.y = (u32)f32_to_bf16(a.z) | ((u32)f32_to_bf16(a.w) << 16);
  r.z = (u32)f32_to_bf16(b.x) | ((u32)f32_to_bf16(b.y) << 16);
  r.w = (u32)f32_to_bf16(b.z) | ((u32)f32_to_bf16(b.w) << 16);
  ((uint4*)o)[i] = r;
}

// ---------- dequant W[K][N] (int 0..15) -> out[N][K] bf16 (transposed) ------
// Group size 128 along K; tile = 64 k x 256 n, one group per tile.
__global__ __launch_bounds__(256) void k_dequant(const int* __restrict__ W,
                                                 const int* __restrict__ Z,
                                                 const float* __restrict__ S,
                                                 u16* __restrict__ out, int K,
                                                 int N) {
  __shared__ u16 ldsT[256 * 66];  // [n_local][k_local], pad to 66 elems
  const int k0 = blockIdx.x * 64, n0 = blockIdx.y * 256;
  const int t = threadIdx.x;
  const int n4 = t & 63;   // n quad
  const int kr = t >> 6;   // 0..3
  const int g = k0 >> 7;
  const int nb = n0 + n4 * 4;
  const int4 z4 = *(const int4*)(Z + (size_t)g * N + nb);
  const float4 s4 = *(const float4*)(S + (size_t)g * N + nb);
#pragma unroll
  for (int pass = 0; pass < 16; ++pass) {
    const int kl = kr + pass * 4;
    const int4 w4 = *(const int4*)(W + (size_t)(k0 + kl) * N + nb);
    ldsT[(n4 * 4 + 0) * 66 + kl] = f32_to_bf16((float)(w4.x - z4.x) * s4.x);
    ldsT[(n4 * 4 + 1) * 66 + kl] = f32_to_bf16((float)(w4.y - z4.y) * s4.y);
    ldsT[(n4 * 4 + 2) * 66 + kl] = f32_to_bf16((float)(w4.z - z4.z) * s4.z);
    ldsT[(n4 * 4 + 3) * 66 + kl] = f32_to_bf16((float)(w4.w - z4.w) * s4.w);
  }
  __syncthreads();
#pragma unroll
  for (int pass = 0; pass < 8; ++pass) {
    const int nl = pass * 32 + (t >> 3);
    const int kc = (t & 7) * 8;  // elems
    const u16* p = &ldsT[nl * 66 + kc];
    const u32 w0 = *(const u32*)(p + 0);
    const u32 w1 = *(const u32*)(p + 2);
    const u32 w2 = *(const u32*)(p + 4);
    const u32 w3 = *(const u32*)(p + 6);
    *(uint4*)(out + (size_t)(n0 + nl) * K + k0 + kc) =
        make_uint4(w0, w1, w2, w3);
  }
}

// ---------- fused gate/up GEMM: h = silu(x@Wg) * (x@Wu) ----------
// X[8192][4096] bf16, WG/WU [14336][4096] bf16 (n-major), Hout[8192][14336]
__global__ __launch_bounds__(256, 2) void k_gemm_gu(
    const u16* __restrict__ X, const u16* __restrict__ WG,
    const u16* __restrict__ WU, u16* __restrict__ Hout) {
  __shared__ u16 lA[128 * 64], lG[128 * 64], lU[128 * 64];
  const int m0 = blockIdx.x * 128, n0 = blockIdx.y * 128;
  const int tid = threadIdx.x, lane = tid & 63, p = lane >> 4, r16 = lane & 15;
  const int wave = tid >> 6, wr = wave >> 1, wc = wave & 1;

  f32x4 aG[4][4], aU[4][4];
  const f32x4 zero = {0.f, 0.f, 0.f, 0.f};
#pragma unroll
  for (int i = 0; i < 4; ++i)
#pragma unroll
    for (int j = 0; j < 4; ++j) {
      aG[i][j] = zero;
      aU[i][j] = zero;
    }

  const char* xb = (const char*)(X + (size_t)m0 * 4096);
  const char* gb = (const char*)(WG + (size_t)n0 * 4096);
  const char* ub = (const char*)(WU + (size_t)n0 * 4096);

  for (int kt = 0; kt < 64; ++kt) {
    const int kb = kt * 128;  // byte offset within a row
    stage_tile(xb + kb, 8192, lA, tid);
    stage_tile(gb + kb, 8192, lG, tid);
    stage_tile(ub + kb, 8192, lU, tid);
    __syncthreads();
#pragma unroll
    for (int ks = 0; ks < 2; ++ks) {
      bf16x8 af[4], gf[4], uf[4];
#pragma unroll
      for (int i = 0; i < 4; ++i)
        af[i] = frag_ld(lA, wr * 64 + i * 16 + r16, ks, p);
#pragma unroll
      for (int j = 0; j < 4; ++j) {
        gf[j] = frag_ld(lG, wc * 64 + j * 16 + r16, ks, p);
        uf[j] = frag_ld(lU, wc * 64 + j * 16 + r16, ks, p);
      }
#pragma unroll
      for (int i = 0; i < 4; ++i)
#pragma unroll
        for (int j = 0; j < 4; ++j) {
          aG[i][j] = __builtin_amdgcn_mfma_f32_16x16x32_bf16(af[i], gf[j],
                                                             aG[i][j], 0, 0, 0);
          aU[i][j] = __builtin_amdgcn_mfma_f32_16x16x32_bf16(af[i], uf[j],
                                                             aU[i][j], 0, 0, 0);
        }
    }
    __syncthreads();
  }
  // epilogue: silu(g)*u -> bf16. C/D map: col=lane&15, row=(lane>>4)*4+reg.
#pragma unroll
  for (int i = 0; i < 4; ++i) {
    const int row = m0 + wr * 64 + i * 16 + p * 4;
#pragma unroll
    for (int j = 0; j < 4; ++j) {
      const int col = n0 + wc * 64 + j * 16 + r16;
      u16* dst = Hout + (size_t)row * 14336 + col;
#pragma unroll
      for (int r = 0; r < 4; ++r) {
        const float gv = aG[i][j][r], uv = aU[i][j][r];
        const float sv = gv / (1.f + __expf(-gv)) * uv;
        dst[(size_t)r * 14336] = f32_to_bf16(sv);
      }
    }
  }
}

// ---------- down GEMM: out = h @ Wd  (fp32 out) ----------
// Hin[8192][14336] bf16, WD[4096][14336] bf16 (n-major), Out[8192][4096] f32
__global__ __launch_bounds__(256, 2) void k_gemm_down(
    const u16* __restrict__ Hin, const u16* __restrict__ WD,
    float* __restrict__ Out) {
  __shared__ u16 lA[128 * 64], lB[128 * 64];
  const int m0 = blockIdx.x * 128, n0 = blockIdx.y * 128;
  const int tid = threadIdx.x, lane = tid & 63, p = lane >> 4, r16 = lane & 15;
  const int wave = tid >> 6, wr = wave >> 1, wc = wave & 1;

  f32x4 acc[4][4];
  const f32x4 zero = {0.f, 0.f, 0.f, 0.f};
#pragma unroll
  for (int i = 0; i < 4; ++i)
#pragma unroll
    for (int j = 0; j < 4; ++j) acc[i][j] = zero;

  const char* ab = (const char*)(Hin + (size_t)m0 * 14336);
  const char* bb = (const char*)(WD + (size_t)n0 * 14336);

  for (int kt = 0; kt < 224; ++kt) {
    const long kb = (long)kt * 128;
    stage_tile(ab + kb, 28672, lA, tid);
    stage_tile(bb + kb, 28672, lB, tid);
    __syncthreads();
#pragma unroll
    for (int ks = 0; ks < 2; ++ks) {
      bf16x8 af[4], bf[4];
#pragma unroll
      for (int i = 0; i < 4; ++i)
        af[i] = frag_ld(lA, wr * 64 + i * 16 + r16, ks, p);
#pragma unroll
      for (int j = 0; j < 4; ++j)
        bf[j] = frag_ld(lB, wc * 64 + j * 16 + r16, ks, p);
#pragma unroll
      for (int i = 0; i < 4; ++i)
#pragma unroll
        for (int j = 0; j < 4; ++j)
          acc[i][j] = __builtin_amdgcn_mfma_f32_16x16x32_bf16(
              af[i], bf[j], acc[i][j], 0, 0, 0);
    }
    __syncthreads();
  }
#pragma unroll
  for (int i = 0; i < 4; ++i) {
    const int row = m0 + wr * 64 + i * 16 + p * 4;
#pragma unroll
    for (int j = 0; j < 4; ++j) {
      const int col = n0 + wc * 64 + j * 16 + r16;
      float* dst = Out + (size_t)row * 4096 + col;
#pragma unroll
      for (int r = 0; r < 4; ++r) dst[(size_t)r * 4096] = acc[i][j][r];
    }
  }
}

// ---------- sentinel fill (ws too small diagnostic) ----------
__global__ void k_fill(float* o, long n, float v) {
  const long i = (long)blockIdx.x * 256 + threadIdx.x;
  if (i < n) o[i] = v;
}

extern "C" void kernel_launch(void* const* d_in, const int* in_sizes, int n_in,
                              void* d_out, int out_size, void* d_ws,
                              size_t ws_size, hipStream_t stream) {
  const float* x = (const float*)d_in[0];
  const int* gw = (const int*)d_in[1];
  const int* gz = (const int*)d_in[2];
  const float* gs = (const float*)d_in[3];
  const int* uw = (const int*)d_in[4];
  const int* uz = (const int*)d_in[5];
  const float* us = (const float*)d_in[6];
  const int* dw = (const int*)d_in[7];
  const int* dz = (const int*)d_in[8];
  const float* dsc = (const float*)d_in[9];
  float* out = (float*)d_out;

  // ws layout (bf16 elems): x 33,554,432 | Wg/Wu/Wd 58,720,256 each | h
  const size_t NX = 33554432UL, NW = 58720256UL, NH = 117440512UL;
  const size_t need = 2UL * (NX + 3UL * NW + NH);  // 654,311,424 B
  if (ws_size < need) {
    // Distinctive sentinel so a too-small workspace is diagnosable from absmax
    k_fill<<<(out_size + 255) / 256, 256, 0, stream>>>(out, out_size, 1.0e6f);
    return;
  }
  u16* wsx = (u16*)d_ws;
  u16* wgq = wsx + NX;
  u16* wuq = wgq + NW;
  u16* wdq = wuq + NW;
  u16* wh = wdq + NW;

  k_convert_x<<<16384, 256, 0, stream>>>(x, wsx);
  dim3 dq1(64, 56);
  k_dequant<<<dq1, 256, 0, stream>>>(gw, gz, gs, wgq, 4096, 14336);
  k_dequant<<<dq1, 256, 0, stream>>>(uw, uz, us, wuq, 4096, 14336);
  dim3 dq2(224, 16);
  k_dequant<<<dq2, 256, 0, stream>>>(dw, dz, dsc, wdq, 14336, 4096);
  dim3 g1(64, 112);
  k_gemm_gu<<<g1, 256, 0, stream>>>(wsx, wgq, wuq, wh);
  dim3 g2(64, 32);
  k_gemm_down<<<g2, 256, 0, stream>>>(wh, wdq, out);
}